// Round 6
// baseline (233.659 us; speedup 1.0000x reference)
//
#include <hip/hip_runtime.h>

// Factored single-row attention (reference returns out[:, -1, :] only).
// ws layout (floats): M2p [0,65536) packed [dd4][t][4]; Wvp [65536,131072)
// packed [d4][t][4]; v0 @131072; c @131328; w1 @131584; w2 @131840;
// dconst (3 doubles) @132096; Sq (2048 dbl) @132608; Qbk (2048 dbl) @136704;
// u/y (2048x256 f32, u overwritten by y) @140800.
//   M2[f][d] = sum_e Wq[e][f] Wk[e][d]  (u = td*(x49@M2) + v0)
//   v0[d] = sum_e bq[e] Wk[e][d];  c[d] = sum_e Wk[e][d]
//   w1[f] = sum_e bk[e] Wq[e][f];  w2[f] = sum_e Wq[e][f]
//   dconst = {sum(bk), bq.bk, sum(bq)}
// Score paths (identical to passing rounds 1-5):
//   q-kept & s-kept : (xs_s.u + q.bk)/16   q-kept & s-mask: NEG*sum(q)/16
//   q-mask & s-kept : NEG*(xs_s.c + sum(bk))/16   both: 256e10/16
// Round-6 restructure: the fused kernel's U/O phases did ~33M broadcast
// ds_read_b128 (~10us/phase of LDS-pipe serialization) behind barriers at
// 20% occupancy. Split into 3 barrier-free kernels: u_gemm / attn / o_gemm.
// xs and y are read via WAVE-UNIFORM global loads (scalarize to s_load,
// no LDS pipe); M2p/Wvp via coalesced b128 + 8-deep register prefetch;
// attn is one wave per batch with td/mask rows lane-held + __shfl broadcast.

namespace {
constexpr int kB = 2048;
constexpr int kT = 50;
constexpr int kD = 256;
constexpr int kThr = 256;
constexpr double kNeg = -100000.0;
constexpr int oM2 = 0;
constexpr int oWvp = 65536;
constexpr int oV0 = 131072;
constexpr int oC = 131328;
constexpr int oW1 = 131584;
constexpr int oW2 = 131840;
constexpr int oDbl = 132096;   // 3 doubles
constexpr int oSq = 132608;    // 2048 doubles
constexpr int oQbk = 136704;   // 2048 doubles
constexpr int oU = 140800;     // 2048*256 floats (u, then y)
}  // namespace

// ---------------- precomp: VERBATIM from round 5 (proven) ----------------
__global__ __launch_bounds__(kThr) void precomp(
    const float* __restrict__ Wq, const float* __restrict__ bq,
    const float* __restrict__ Wk, const float* __restrict__ bk,
    const float* __restrict__ Wv, float* __restrict__ ws) {
  const int t = threadIdx.x;
  const int wave = t >> 6;
  const int lane = t & 63;
  const int blk = blockIdx.x;
  __shared__ float coefL[kD];
  __shared__ double red[3][4];

  if (blk < 256) {
    const int a = blk;
    coefL[t] = Wq[(size_t)t * kD + a];
    __syncthreads();
    const float* kcol = Wk + t;
    float pre[8];
#pragma unroll
    for (int k = 0; k < 8; ++k) pre[k] = kcol[(size_t)k * kD];
    float acc = 0.f;
    for (int j0 = 0; j0 < kD; j0 += 8) {
      float cur[8];
#pragma unroll
      for (int k = 0; k < 8; ++k) cur[k] = pre[k];
      const int nx = (j0 + 8 < kD) ? (j0 + 8) : 0;
#pragma unroll
      for (int k = 0; k < 8; ++k) pre[k] = kcol[(size_t)(nx + k) * kD];
#pragma unroll
      for (int k = 0; k < 8; ++k) acc += coefL[j0 + k] * cur[k];
    }
    ws[oM2 + (a >> 2) * 1024 + 4 * t + (a & 3)] = acc;
  } else if (blk < 258) {
    const float* W = (blk == 256) ? Wk : Wq;
    const float* coef = (blk == 256) ? bq : bk;
    coefL[t] = coef[t];
    __syncthreads();
    const float* col = W + t;
    float pre[8];
#pragma unroll
    for (int k = 0; k < 8; ++k) pre[k] = col[(size_t)k * kD];
    double a0 = 0.0, a1 = 0.0;
    for (int j0 = 0; j0 < kD; j0 += 8) {
      float cur[8];
#pragma unroll
      for (int k = 0; k < 8; ++k) cur[k] = pre[k];
      const int nx = (j0 + 8 < kD) ? (j0 + 8) : 0;
#pragma unroll
      for (int k = 0; k < 8; ++k) pre[k] = col[(size_t)(nx + k) * kD];
#pragma unroll
      for (int k = 0; k < 8; ++k) {
        const double w = (double)cur[k];
        a0 += (double)coefL[j0 + k] * w;
        a1 += w;
      }
    }
    if (blk == 256) {
      ws[oV0 + t] = (float)a0;
      ws[oC + t] = (float)a1;
    } else {
      ws[oW1 + t] = (float)a0;
      ws[oW2 + t] = (float)a1;
      double p0 = (double)bk[t];
      double p1 = (double)bq[t] * (double)bk[t];
      double p2 = (double)bq[t];
#pragma unroll
      for (int off = 32; off; off >>= 1) {
        p0 += __shfl_xor(p0, off);
        p1 += __shfl_xor(p1, off);
        p2 += __shfl_xor(p2, off);
      }
      if (lane == 0) {
        red[0][wave] = p0;
        red[1][wave] = p1;
        red[2][wave] = p2;
      }
      __syncthreads();
      if (t == 0) {
        double* dc = (double*)(ws + oDbl);
        dc[0] = red[0][0] + red[0][1] + red[0][2] + red[0][3];
        dc[1] = red[1][0] + red[1][1] + red[1][2] + red[1][3];
        dc[2] = red[2][0] + red[2][1] + red[2][2] + red[2][3];
      }
    }
  } else {
    const int d4b = (blk - 258) * 4;
    float4 in[4];
#pragma unroll
    for (int k = 0; k < 4; ++k)
      in[k] = *(const float4*)(Wv + (size_t)t * kD + 4 * (d4b + k));
    float4* Wvp = (float4*)(ws + oWvp);
#pragma unroll
    for (int k = 0; k < 4; ++k) Wvp[(size_t)(d4b + k) * kD + t] = in[k];
  }
}

// ---------------- u_gemm: u = td*(x49@M2)+v0, plus fp64 scalars ----------
__global__ __launch_bounds__(kThr) void u_gemm(const float* __restrict__ x,
                                               const float* __restrict__ td,
                                               float* __restrict__ ws) {
  const int t = threadIdx.x;
  const int wave = t >> 6;
  const int lane = t & 63;
  const int b0 = blockIdx.x * 4;
  const double* dc = (const double*)(ws + oDbl);

  // per-batch fp64 scalars: wave j -> batch b0+j
  {
    const int b = b0 + wave;
    const float4 xv =
        ((const float4*)(x + ((size_t)b * kT + kT - 1) * kD))[lane];
    const float4 a1 = ((const float4*)(ws + oW1))[lane];
    const float4 a2 = ((const float4*)(ws + oW2))[lane];
    double s1 = (double)xv.x * a1.x + (double)xv.y * a1.y +
                (double)xv.z * a1.z + (double)xv.w * a1.w;
    double s2 = (double)xv.x * a2.x + (double)xv.y * a2.y +
                (double)xv.z * a2.z + (double)xv.w * a2.w;
#pragma unroll
    for (int off = 32; off; off >>= 1) {
      s1 += __shfl_xor(s1, off);
      s2 += __shfl_xor(s2, off);
    }
    if (lane == 0) {
      const double tdd = (double)td[(size_t)b * kT + kT - 1];
      ((double*)(ws + oQbk))[b] = tdd * s1 + dc[1];
      ((double*)(ws + oSq))[b] = tdd * s2 + dc[2];
    }
  }

  // u[b0+j][t] = td_j * sum_k4 x49_j[k4].M2p[k4][t] + v0[t]
  const float4* M2v = (const float4*)(ws + oM2);
  const float4* r0 = (const float4*)(x + ((size_t)(b0 + 0) * kT + kT - 1) * kD);
  const float4* r1 = (const float4*)(x + ((size_t)(b0 + 1) * kT + kT - 1) * kD);
  const float4* r2 = (const float4*)(x + ((size_t)(b0 + 2) * kT + kT - 1) * kD);
  const float4* r3 = (const float4*)(x + ((size_t)(b0 + 3) * kT + kT - 1) * kD);
  const float td0 = td[(size_t)(b0 + 0) * kT + kT - 1];
  const float td1 = td[(size_t)(b0 + 1) * kT + kT - 1];
  const float td2 = td[(size_t)(b0 + 2) * kT + kT - 1];
  const float td3 = td[(size_t)(b0 + 3) * kT + kT - 1];

  float4 pre[8];
#pragma unroll
  for (int k = 0; k < 8; ++k) pre[k] = M2v[(size_t)k * kD + t];
  float acc0 = 0.f, acc1 = 0.f, acc2 = 0.f, acc3 = 0.f;
  for (int j0 = 0; j0 < 64; j0 += 8) {
    float4 cur[8];
#pragma unroll
    for (int k = 0; k < 8; ++k) cur[k] = pre[k];
    const int nx = (j0 + 8 < 64) ? (j0 + 8) : 0;
#pragma unroll
    for (int k = 0; k < 8; ++k) pre[k] = M2v[(size_t)(nx + k) * kD + t];
#pragma unroll
    for (int k = 0; k < 8; ++k) {
      const float4 m = cur[k];
      const float4 x0 = r0[j0 + k];  // wave-uniform -> s_load
      const float4 x1 = r1[j0 + k];
      const float4 x2 = r2[j0 + k];
      const float4 x3 = r3[j0 + k];
      acc0 += x0.x * m.x + x0.y * m.y + x0.z * m.z + x0.w * m.w;
      acc1 += x1.x * m.x + x1.y * m.y + x1.z * m.z + x1.w * m.w;
      acc2 += x2.x * m.x + x2.y * m.y + x2.z * m.z + x2.w * m.w;
      acc3 += x3.x * m.x + x3.y * m.y + x3.z * m.z + x3.w * m.w;
    }
  }
  const float v0t = ws[oV0 + t];
  ws[oU + (size_t)(b0 + 0) * kD + t] = td0 * acc0 + v0t;
  ws[oU + (size_t)(b0 + 1) * kD + t] = td1 * acc1 + v0t;
  ws[oU + (size_t)(b0 + 2) * kD + t] = td2 * acc2 + v0t;
  ws[oU + (size_t)(b0 + 3) * kD + t] = td3 * acc3 + v0t;
}

// ---------------- attn: one wave per batch, zero LDS/barriers -------------
__global__ __launch_bounds__(kThr) void attn(const float* __restrict__ x,
                                             const int* __restrict__ mask,
                                             const float* __restrict__ td,
                                             float* __restrict__ ws) {
  const int t = threadIdx.x;
  const int wave = t >> 6;
  const int lane = t & 63;
  const int b = blockIdx.x * 4 + wave;

  const float mtd = (lane < kT) ? td[(size_t)b * kT + lane] : 0.f;
  const int mmk = (lane < kT) ? mask[(size_t)b * kT + lane] : 0;
  const int mqg = __shfl(mmk, kT - 1);

  const float4 u4 = ((const float4*)(ws + oU))[(size_t)b * 64 + lane];
  const float4 c4 = ((const float4*)(ws + oC))[lane];
  const float4 v4 = mqg ? u4 : c4;

  const double* dcp = (const double*)(ws + oDbl);
  const double sbkd = dcp[0];
  const double Sq = ((const double*)(ws + oSq))[b];
  const double Qbk = ((const double*)(ws + oQbk))[b];
  const double Cm = kNeg * Sq * 0.0625;
  const double Cbb = 256.0 * 1.0e10 * 0.0625;

  const float4* xrow = (const float4*)(x + (size_t)b * kT * kD);
  double m = -1.0e300;
  float l = 0.f;
  float4 y = {0.f, 0.f, 0.f, 0.f};

  float4 n0 = xrow[0 * 64 + lane];
  float4 n1 = xrow[1 * 64 + lane];
  float4 n2 = xrow[2 * 64 + lane];
  float4 n3 = xrow[3 * 64 + lane];
  for (int s = 0; s < 52; s += 4) {
    const float4 r0 = n0, r1 = n1, r2 = n2, r3 = n3;
    {
      const int p0 = (s + 4 < kT) ? s + 4 : kT - 1;
      const int p1 = (s + 5 < kT) ? s + 5 : kT - 1;
      const int p2 = (s + 6 < kT) ? s + 6 : kT - 1;
      const int p3 = (s + 7 < kT) ? s + 7 : kT - 1;
      n0 = xrow[p0 * 64 + lane];
      n1 = xrow[p1 * 64 + lane];
      n2 = xrow[p2 * 64 + lane];
      n3 = xrow[p3 * 64 + lane];
    }
    const int s1i = s + 1, s2i = s + 2, s3i = s + 3;
    const int c0 = s;
    const int c1 = (s1i < kT) ? s1i : kT - 1;
    const int c2 = (s2i < kT) ? s2i : kT - 1;
    const int c3 = (s3i < kT) ? s3i : kT - 1;
    const float tv0 = __shfl(mtd, c0);
    const float tv1 = __shfl(mtd, c1);
    const float tv2 = __shfl(mtd, c2);
    const float tv3 = __shfl(mtd, c3);
    float4 a0, a1, a2, a3;
    a0.x = r0.x * tv0; a0.y = r0.y * tv0; a0.z = r0.z * tv0; a0.w = r0.w * tv0;
    a1.x = r1.x * tv1; a1.y = r1.y * tv1; a1.z = r1.z * tv1; a1.w = r1.w * tv1;
    a2.x = r2.x * tv2; a2.y = r2.y * tv2; a2.z = r2.z * tv2; a2.w = r2.w * tv2;
    a3.x = r3.x * tv3; a3.y = r3.y * tv3; a3.z = r3.z * tv3; a3.w = r3.w * tv3;
    float p0 = a0.x * v4.x + a0.y * v4.y + a0.z * v4.z + a0.w * v4.w;
    float p1 = a1.x * v4.x + a1.y * v4.y + a1.z * v4.z + a1.w * v4.w;
    float p2 = a2.x * v4.x + a2.y * v4.y + a2.z * v4.z + a2.w * v4.w;
    float p3 = a3.x * v4.x + a3.y * v4.y + a3.z * v4.z + a3.w * v4.w;
#pragma unroll
    for (int off = 32; off; off >>= 1) {
      p0 += __shfl_xor(p0, off);
      p1 += __shfl_xor(p1, off);
      p2 += __shfl_xor(p2, off);
      p3 += __shfl_xor(p3, off);
    }
    const int ms0 = __shfl(mmk, c0);
    const int ms1 = __shfl(mmk, c1);
    const int ms2 = __shfl(mmk, c2);
    const int ms3 = __shfl(mmk, c3);
    double sc0, sc1, sc2, sc3;
    if (mqg) {
      sc0 = ms0 ? ((double)p0 + Qbk) * 0.0625 : Cm;
      sc1 = ms1 ? ((double)p1 + Qbk) * 0.0625 : Cm;
      sc2 = ms2 ? ((double)p2 + Qbk) * 0.0625 : Cm;
      sc3 = ms3 ? ((double)p3 + Qbk) * 0.0625 : Cm;
    } else {
      sc0 = ms0 ? kNeg * ((double)p0 + sbkd) * 0.0625 : Cbb;
      sc1 = ms1 ? kNeg * ((double)p1 + sbkd) * 0.0625 : Cbb;
      sc2 = ms2 ? kNeg * ((double)p2 + sbkd) * 0.0625 : Cbb;
      sc3 = ms3 ? kNeg * ((double)p3 + sbkd) * 0.0625 : Cbb;
    }
    if (s1i >= kT) sc1 = -1.0e300;
    if (s2i >= kT) sc2 = -1.0e300;
    if (s3i >= kT) sc3 = -1.0e300;
    double mnew = m;
    if (sc0 > mnew) mnew = sc0;
    if (sc1 > mnew) mnew = sc1;
    if (sc2 > mnew) mnew = sc2;
    if (sc3 > mnew) mnew = sc3;
    const float al = expf((float)(m - mnew));
    const float e0 = expf((float)(sc0 - mnew));
    const float e1 = expf((float)(sc1 - mnew));
    const float e2 = expf((float)(sc2 - mnew));
    const float e3 = expf((float)(sc3 - mnew));
    m = mnew;
    l = l * al + e0 + e1 + e2 + e3;
    y.x = y.x * al + e0 * a0.x + e1 * a1.x + e2 * a2.x + e3 * a3.x;
    y.y = y.y * al + e0 * a0.y + e1 * a1.y + e2 * a2.y + e3 * a3.y;
    y.z = y.z * al + e0 * a0.z + e1 * a1.z + e2 * a2.z + e3 * a3.z;
    y.w = y.w * al + e0 * a0.w + e1 * a1.w + e2 * a2.w + e3 * a3.w;
  }
  const float inv = 1.0f / l;
  y.x *= inv; y.y *= inv; y.z *= inv; y.w *= inv;
  // overwrite u slot with y (u4 already consumed by this wave; rows disjoint)
  ((float4*)(ws + oU))[(size_t)b * 64 + lane] = y;
}

// ---------------- o_gemm: out = y@WvT + bv --------------------------------
__global__ __launch_bounds__(kThr) void o_gemm(const float* __restrict__ bv,
                                               const float* __restrict__ ws,
                                               float* __restrict__ out) {
  const int t = threadIdx.x;
  const int b0 = blockIdx.x * 4;
  const float4* Wvv = (const float4*)(ws + oWvp);
  const float4* y0 = (const float4*)(ws + oU + (size_t)(b0 + 0) * kD);
  const float4* y1 = (const float4*)(ws + oU + (size_t)(b0 + 1) * kD);
  const float4* y2 = (const float4*)(ws + oU + (size_t)(b0 + 2) * kD);
  const float4* y3 = (const float4*)(ws + oU + (size_t)(b0 + 3) * kD);

  float4 pre[8];
#pragma unroll
  for (int k = 0; k < 8; ++k) pre[k] = Wvv[(size_t)k * kD + t];
  float acc0 = 0.f, acc1 = 0.f, acc2 = 0.f, acc3 = 0.f;
  for (int j0 = 0; j0 < 64; j0 += 8) {
    float4 cur[8];
#pragma unroll
    for (int k = 0; k < 8; ++k) cur[k] = pre[k];
    const int nx = (j0 + 8 < 64) ? (j0 + 8) : 0;
#pragma unroll
    for (int k = 0; k < 8; ++k) pre[k] = Wvv[(size_t)(nx + k) * kD + t];
#pragma unroll
    for (int k = 0; k < 8; ++k) {
      const float4 m = cur[k];
      const float4 a0 = y0[j0 + k];  // wave-uniform -> s_load
      const float4 a1 = y1[j0 + k];
      const float4 a2 = y2[j0 + k];
      const float4 a3 = y3[j0 + k];
      acc0 += a0.x * m.x + a0.y * m.y + a0.z * m.z + a0.w * m.w;
      acc1 += a1.x * m.x + a1.y * m.y + a1.z * m.z + a1.w * m.w;
      acc2 += a2.x * m.x + a2.y * m.y + a2.z * m.z + a2.w * m.w;
      acc3 += a3.x * m.x + a3.y * m.y + a3.z * m.z + a3.w * m.w;
    }
  }
  const float bvt = bv[t];
  out[(size_t)(b0 + 0) * kD + t] = acc0 + bvt;
  out[(size_t)(b0 + 1) * kD + t] = acc1 + bvt;
  out[(size_t)(b0 + 2) * kD + t] = acc2 + bvt;
  out[(size_t)(b0 + 3) * kD + t] = acc3 + bvt;
}

extern "C" void kernel_launch(void* const* d_in, const int* in_sizes, int n_in,
                              void* d_out, int out_size, void* d_ws,
                              size_t ws_size, hipStream_t stream) {
  const float* x = (const float*)d_in[0];
  const int* mask = (const int*)d_in[1];
  const float* td = (const float*)d_in[2];
  const float* Wq = (const float*)d_in[3];
  const float* bq = (const float*)d_in[4];
  const float* Wk = (const float*)d_in[5];
  const float* bk = (const float*)d_in[6];
  const float* Wv = (const float*)d_in[7];
  const float* bv = (const float*)d_in[8];
  float* ws = (float*)d_ws;  // needs ~2.7 MB
  float* out = (float*)d_out;
  (void)in_sizes; (void)n_in; (void)out_size; (void)ws_size;

  hipLaunchKernelGGL(precomp, dim3(274), dim3(kThr), 0, stream, Wq, bq, Wk, bk,
                     Wv, ws);
  hipLaunchKernelGGL(u_gemm, dim3(kB / 4), dim3(kThr), 0, stream, x, td, ws);
  hipLaunchKernelGGL(attn, dim3(kB / 4), dim3(kThr), 0, stream, x, mask, td,
                     ws);
  hipLaunchKernelGGL(o_gemm, dim3(kB / 4), dim3(kThr), 0, stream, bv, ws, out);
}

// Round 7
// 209.338 us; speedup vs baseline: 1.1162x; 1.1162x over previous
//
#include <hip/hip_runtime.h>

// Factored single-row attention (reference returns out[:, -1, :] only).
// ws layout (floats): M2p [0,65536) packed [k4][e][4]; Wvp [65536,131072)
// packed [d4][e][4]; v0 @131072; c @131328; w1 @131584; w2 @131840;
// dconst {sum(bk), bq.bk, sum(bq)} (3 doubles) @132096.
//   M2[f][d] = sum_e Wq[e][f] Wk[e][d]  (u = td*(x49@M2) + v0)
//   v0[d] = sum_e bq[e] Wk[e][d];  c[d] = sum_e Wk[e][d]
//   w1[f] = sum_e bk[e] Wq[e][f];  w2[f] = sum_e Wq[e][f]
// Score paths (identical to passing rounds 1-6):
//   q-kept & s-kept : (xs_s.u + q.bk)/16   q-kept & s-mask: NEG*sum(q)/16
//   q-mask & s-kept : NEG*(xs_s.c + sum(bk))/16   both: 256e10/16
// Round-7: ONE fused main kernel, ZERO barriers. grid 1024 x 64thr: each
// wave owns 2 batches end-to-end (u -> attn -> out), so nothing round-trips
// through global and no cross-wave sync exists. U/O phases: lane owns
// strided output dims {l,64+l,128+l,192+l} -> 4 perfectly-coalesced b128
// M2/Wvp streams with 8-deep prefetch; xs/y broadcast via 1 wave-local
// ds_read_b128 per k4-step (round-5's 4096 broadcast ds_reads -> 64).
// attn body is round-6's proven wave-per-batch stream (lane-held td/mask).

namespace {
constexpr int kB = 2048;
constexpr int kT = 50;
constexpr int kD = 256;
constexpr double kNeg = -100000.0;
constexpr int oM2 = 0;
constexpr int oWvp = 65536;
constexpr int oV0 = 131072;
constexpr int oC = 131328;
constexpr int oW1 = 131584;
constexpr int oW2 = 131840;
constexpr int oDbl = 132096;  // 3 doubles
}  // namespace

// ---------------- precomp: VERBATIM from rounds 5-6 (proven) --------------
__global__ __launch_bounds__(256) void precomp(
    const float* __restrict__ Wq, const float* __restrict__ bq,
    const float* __restrict__ Wk, const float* __restrict__ bk,
    const float* __restrict__ Wv, float* __restrict__ ws) {
  const int t = threadIdx.x;
  const int wave = t >> 6;
  const int lane = t & 63;
  const int blk = blockIdx.x;
  __shared__ float coefL[kD];
  __shared__ double red[3][4];

  if (blk < 256) {
    const int a = blk;
    coefL[t] = Wq[(size_t)t * kD + a];
    __syncthreads();
    const float* kcol = Wk + t;
    float pre[8];
#pragma unroll
    for (int k = 0; k < 8; ++k) pre[k] = kcol[(size_t)k * kD];
    float acc = 0.f;
    for (int j0 = 0; j0 < kD; j0 += 8) {
      float cur[8];
#pragma unroll
      for (int k = 0; k < 8; ++k) cur[k] = pre[k];
      const int nx = (j0 + 8 < kD) ? (j0 + 8) : 0;
#pragma unroll
      for (int k = 0; k < 8; ++k) pre[k] = kcol[(size_t)(nx + k) * kD];
#pragma unroll
      for (int k = 0; k < 8; ++k) acc += coefL[j0 + k] * cur[k];
    }
    ws[oM2 + (a >> 2) * 1024 + 4 * t + (a & 3)] = acc;
  } else if (blk < 258) {
    const float* W = (blk == 256) ? Wk : Wq;
    const float* coef = (blk == 256) ? bq : bk;
    coefL[t] = coef[t];
    __syncthreads();
    const float* col = W + t;
    float pre[8];
#pragma unroll
    for (int k = 0; k < 8; ++k) pre[k] = col[(size_t)k * kD];
    double a0 = 0.0, a1 = 0.0;
    for (int j0 = 0; j0 < kD; j0 += 8) {
      float cur[8];
#pragma unroll
      for (int k = 0; k < 8; ++k) cur[k] = pre[k];
      const int nx = (j0 + 8 < kD) ? (j0 + 8) : 0;
#pragma unroll
      for (int k = 0; k < 8; ++k) pre[k] = col[(size_t)(nx + k) * kD];
#pragma unroll
      for (int k = 0; k < 8; ++k) {
        const double w = (double)cur[k];
        a0 += (double)coefL[j0 + k] * w;
        a1 += w;
      }
    }
    if (blk == 256) {
      ws[oV0 + t] = (float)a0;
      ws[oC + t] = (float)a1;
    } else {
      ws[oW1 + t] = (float)a0;
      ws[oW2 + t] = (float)a1;
      double p0 = (double)bk[t];
      double p1 = (double)bq[t] * (double)bk[t];
      double p2 = (double)bq[t];
#pragma unroll
      for (int off = 32; off; off >>= 1) {
        p0 += __shfl_xor(p0, off);
        p1 += __shfl_xor(p1, off);
        p2 += __shfl_xor(p2, off);
      }
      if (lane == 0) {
        red[0][wave] = p0;
        red[1][wave] = p1;
        red[2][wave] = p2;
      }
      __syncthreads();
      if (t == 0) {
        double* dcw = (double*)(ws + oDbl);
        dcw[0] = red[0][0] + red[0][1] + red[0][2] + red[0][3];
        dcw[1] = red[1][0] + red[1][1] + red[1][2] + red[1][3];
        dcw[2] = red[2][0] + red[2][1] + red[2][2] + red[2][3];
      }
    }
  } else {
    const int d4b = (blk - 258) * 4;
    float4 in[4];
#pragma unroll
    for (int k = 0; k < 4; ++k)
      in[k] = *(const float4*)(Wv + (size_t)t * kD + 4 * (d4b + k));
    float4* Wvp = (float4*)(ws + oWvp);
#pragma unroll
    for (int k = 0; k < 4; ++k) Wvp[(size_t)(d4b + k) * kD + t] = in[k];
  }
}

// ---------------- fused main: u -> attn -> out, one wave = 2 batches ------
__global__ __launch_bounds__(64) void fused_main(
    const float* __restrict__ x, const int* __restrict__ mask,
    const float* __restrict__ td, const float* __restrict__ bv,
    const float* __restrict__ ws, float* __restrict__ out) {
  const int lane = threadIdx.x;  // block == one wave
  const int b0 = blockIdx.x * 2;
  __shared__ __align__(16) float xsL[2][kD];
  __shared__ __align__(16) float uL[2][kD];
  __shared__ __align__(16) float yL[2][kD];

  const double* dc = (const double*)(ws + oDbl);
  const float4* M2v = (const float4*)(ws + oM2);
  const float4* Wvv = (const float4*)(ws + oWvp);

  // ---- early loads: td/mask rows lane-held; small vectors ----
  const float mtd0 = (lane < kT) ? td[(size_t)(b0 + 0) * kT + lane] : 0.f;
  const float mtd1 = (lane < kT) ? td[(size_t)(b0 + 1) * kT + lane] : 0.f;
  const int mmk0 = (lane < kT) ? mask[(size_t)(b0 + 0) * kT + lane] : 0;
  const int mmk1 = (lane < kT) ? mask[(size_t)(b0 + 1) * kT + lane] : 0;
  const float4 c4 = ((const float4*)(ws + oC))[lane];
  const float4 a1 = ((const float4*)(ws + oW1))[lane];
  const float4 a2 = ((const float4*)(ws + oW2))[lane];

  // ---- per-batch fp64 scalars + xs staging (wave-local, no barrier) ----
  double Qbk[2], Sq[2];
#pragma unroll
  for (int j = 0; j < 2; ++j) {
    const int b = b0 + j;
    const float tdl = __shfl(j ? mtd1 : mtd0, kT - 1);
    const float4 xv =
        ((const float4*)(x + ((size_t)b * kT + kT - 1) * kD))[lane];
    double s1 = (double)xv.x * a1.x + (double)xv.y * a1.y +
                (double)xv.z * a1.z + (double)xv.w * a1.w;
    double s2 = (double)xv.x * a2.x + (double)xv.y * a2.y +
                (double)xv.z * a2.z + (double)xv.w * a2.w;
#pragma unroll
    for (int off = 32; off; off >>= 1) {
      s1 += __shfl_xor(s1, off);
      s2 += __shfl_xor(s2, off);
    }
    Qbk[j] = (double)tdl * s1 + dc[1];
    Sq[j] = (double)tdl * s2 + dc[2];
    float4 xs;
    xs.x = xv.x * tdl; xs.y = xv.y * tdl;
    xs.z = xv.z * tdl; xs.w = xv.w * tdl;
    *(float4*)(&xsL[j][4 * lane]) = xs;
  }

  // ---- U phase: lane owns dims {l,64+l,128+l,192+l}; coalesced M2 stream,
  //      8-deep prefetch; xs broadcast via wave-local ds_read_b128 ----
  {
    float4 A[4], B[4];
#pragma unroll
    for (int g = 0; g < 4; ++g) {
      A[g] = M2v[(size_t)0 * kD + 64 * g + lane];
      B[g] = M2v[(size_t)1 * kD + 64 * g + lane];
    }
    float accU[2][4] = {{0.f, 0.f, 0.f, 0.f}, {0.f, 0.f, 0.f, 0.f}};
    for (int k4 = 0; k4 < 64; k4 += 2) {
      float4 c0[4], c1[4];
#pragma unroll
      for (int g = 0; g < 4; ++g) { c0[g] = A[g]; c1[g] = B[g]; }
      const int n0 = (k4 + 2 < 64) ? k4 + 2 : 0;
      const int n1 = (k4 + 3 < 64) ? k4 + 3 : 1;
#pragma unroll
      for (int g = 0; g < 4; ++g) {
        A[g] = M2v[(size_t)n0 * kD + 64 * g + lane];
        B[g] = M2v[(size_t)n1 * kD + 64 * g + lane];
      }
      const float4 x00 = *(const float4*)(&xsL[0][4 * k4]);
      const float4 x01 = *(const float4*)(&xsL[0][4 * (k4 + 1)]);
      const float4 x10 = *(const float4*)(&xsL[1][4 * k4]);
      const float4 x11 = *(const float4*)(&xsL[1][4 * (k4 + 1)]);
#pragma unroll
      for (int g = 0; g < 4; ++g) {
        accU[0][g] += x00.x * c0[g].x + x00.y * c0[g].y + x00.z * c0[g].z +
                      x00.w * c0[g].w + x01.x * c1[g].x + x01.y * c1[g].y +
                      x01.z * c1[g].z + x01.w * c1[g].w;
        accU[1][g] += x10.x * c0[g].x + x10.y * c0[g].y + x10.z * c0[g].z +
                      x10.w * c0[g].w + x11.x * c1[g].x + x11.y * c1[g].y +
                      x11.z * c1[g].z + x11.w * c1[g].w;
      }
    }
#pragma unroll
    for (int g = 0; g < 4; ++g) {
      const float v0g = ws[oV0 + 64 * g + lane];
      uL[0][64 * g + lane] = accU[0][g] + v0g;
      uL[1][64 * g + lane] = accU[1][g] + v0g;
    }
  }

  // ---- attention: round-6 proven body, batch j = 0,1 sequentially ----
  const double sbkd = dc[0];
  const double Cbb = 256.0 * 1.0e10 * 0.0625;
#pragma unroll 1
  for (int j = 0; j < 2; ++j) {
    const int b = b0 + j;
    const float mtd = j ? mtd1 : mtd0;
    const int mmk = j ? mmk1 : mmk0;
    const int mqg = __shfl(mmk, kT - 1);
    const float4 u4 = *(const float4*)(&uL[j][4 * lane]);
    const float4 v4 = mqg ? u4 : c4;
    const double Cm = kNeg * Sq[j] * 0.0625;
    const double Qb = Qbk[j];

    const float4* xrow = (const float4*)(x + (size_t)b * kT * kD);
    double m = -1.0e300;
    float l = 0.f;
    float4 y = {0.f, 0.f, 0.f, 0.f};

    float4 n0 = xrow[0 * 64 + lane];
    float4 n1 = xrow[1 * 64 + lane];
    float4 n2 = xrow[2 * 64 + lane];
    float4 n3 = xrow[3 * 64 + lane];
    for (int s = 0; s < 52; s += 4) {
      const float4 r0 = n0, r1 = n1, r2 = n2, r3 = n3;
      {
        const int p0 = (s + 4 < kT) ? s + 4 : kT - 1;
        const int p1 = (s + 5 < kT) ? s + 5 : kT - 1;
        const int p2 = (s + 6 < kT) ? s + 6 : kT - 1;
        const int p3 = (s + 7 < kT) ? s + 7 : kT - 1;
        n0 = xrow[p0 * 64 + lane];
        n1 = xrow[p1 * 64 + lane];
        n2 = xrow[p2 * 64 + lane];
        n3 = xrow[p3 * 64 + lane];
      }
      const int s1i = s + 1, s2i = s + 2, s3i = s + 3;
      const int cc0 = s;
      const int cc1 = (s1i < kT) ? s1i : kT - 1;
      const int cc2 = (s2i < kT) ? s2i : kT - 1;
      const int cc3 = (s3i < kT) ? s3i : kT - 1;
      const float tv0 = __shfl(mtd, cc0);
      const float tv1 = __shfl(mtd, cc1);
      const float tv2 = __shfl(mtd, cc2);
      const float tv3 = __shfl(mtd, cc3);
      float4 a0, aa1, a2v, a3;
      a0.x = r0.x * tv0; a0.y = r0.y * tv0; a0.z = r0.z * tv0; a0.w = r0.w * tv0;
      aa1.x = r1.x * tv1; aa1.y = r1.y * tv1; aa1.z = r1.z * tv1; aa1.w = r1.w * tv1;
      a2v.x = r2.x * tv2; a2v.y = r2.y * tv2; a2v.z = r2.z * tv2; a2v.w = r2.w * tv2;
      a3.x = r3.x * tv3; a3.y = r3.y * tv3; a3.z = r3.z * tv3; a3.w = r3.w * tv3;
      float p0 = a0.x * v4.x + a0.y * v4.y + a0.z * v4.z + a0.w * v4.w;
      float p1 = aa1.x * v4.x + aa1.y * v4.y + aa1.z * v4.z + aa1.w * v4.w;
      float p2 = a2v.x * v4.x + a2v.y * v4.y + a2v.z * v4.z + a2v.w * v4.w;
      float p3 = a3.x * v4.x + a3.y * v4.y + a3.z * v4.z + a3.w * v4.w;
#pragma unroll
      for (int off = 32; off; off >>= 1) {
        p0 += __shfl_xor(p0, off);
        p1 += __shfl_xor(p1, off);
        p2 += __shfl_xor(p2, off);
        p3 += __shfl_xor(p3, off);
      }
      const int ms0 = __shfl(mmk, cc0);
      const int ms1 = __shfl(mmk, cc1);
      const int ms2 = __shfl(mmk, cc2);
      const int ms3 = __shfl(mmk, cc3);
      double sc0, sc1, sc2, sc3;
      if (mqg) {
        sc0 = ms0 ? ((double)p0 + Qb) * 0.0625 : Cm;
        sc1 = ms1 ? ((double)p1 + Qb) * 0.0625 : Cm;
        sc2 = ms2 ? ((double)p2 + Qb) * 0.0625 : Cm;
        sc3 = ms3 ? ((double)p3 + Qb) * 0.0625 : Cm;
      } else {
        sc0 = ms0 ? kNeg * ((double)p0 + sbkd) * 0.0625 : Cbb;
        sc1 = ms1 ? kNeg * ((double)p1 + sbkd) * 0.0625 : Cbb;
        sc2 = ms2 ? kNeg * ((double)p2 + sbkd) * 0.0625 : Cbb;
        sc3 = ms3 ? kNeg * ((double)p3 + sbkd) * 0.0625 : Cbb;
      }
      if (s1i >= kT) sc1 = -1.0e300;
      if (s2i >= kT) sc2 = -1.0e300;
      if (s3i >= kT) sc3 = -1.0e300;
      double mnew = m;
      if (sc0 > mnew) mnew = sc0;
      if (sc1 > mnew) mnew = sc1;
      if (sc2 > mnew) mnew = sc2;
      if (sc3 > mnew) mnew = sc3;
      const float al = expf((float)(m - mnew));
      const float e0 = expf((float)(sc0 - mnew));
      const float e1 = expf((float)(sc1 - mnew));
      const float e2 = expf((float)(sc2 - mnew));
      const float e3 = expf((float)(sc3 - mnew));
      m = mnew;
      l = l * al + e0 + e1 + e2 + e3;
      y.x = y.x * al + e0 * a0.x + e1 * aa1.x + e2 * a2v.x + e3 * a3.x;
      y.y = y.y * al + e0 * a0.y + e1 * aa1.y + e2 * a2v.y + e3 * a3.y;
      y.z = y.z * al + e0 * a0.z + e1 * aa1.z + e2 * a2v.z + e3 * a3.z;
      y.w = y.w * al + e0 * a0.w + e1 * aa1.w + e2 * a2v.w + e3 * a3.w;
    }
    const float inv = 1.0f / l;
    y.x *= inv; y.y *= inv; y.z *= inv; y.w *= inv;
    *(float4*)(&yL[j][4 * lane]) = y;
  }

  // ---- O phase: mirror of U with Wvp / yL; coalesced out stores ----
  {
    float4 A[4], B[4];
#pragma unroll
    for (int g = 0; g < 4; ++g) {
      A[g] = Wvv[(size_t)0 * kD + 64 * g + lane];
      B[g] = Wvv[(size_t)1 * kD + 64 * g + lane];
    }
    float accO[2][4] = {{0.f, 0.f, 0.f, 0.f}, {0.f, 0.f, 0.f, 0.f}};
    for (int k4 = 0; k4 < 64; k4 += 2) {
      float4 c0[4], c1[4];
#pragma unroll
      for (int g = 0; g < 4; ++g) { c0[g] = A[g]; c1[g] = B[g]; }
      const int n0 = (k4 + 2 < 64) ? k4 + 2 : 0;
      const int n1 = (k4 + 3 < 64) ? k4 + 3 : 1;
#pragma unroll
      for (int g = 0; g < 4; ++g) {
        A[g] = Wvv[(size_t)n0 * kD + 64 * g + lane];
        B[g] = Wvv[(size_t)n1 * kD + 64 * g + lane];
      }
      const float4 y00 = *(const float4*)(&yL[0][4 * k4]);
      const float4 y01 = *(const float4*)(&yL[0][4 * (k4 + 1)]);
      const float4 y10 = *(const float4*)(&yL[1][4 * k4]);
      const float4 y11 = *(const float4*)(&yL[1][4 * (k4 + 1)]);
#pragma unroll
      for (int g = 0; g < 4; ++g) {
        accO[0][g] += y00.x * c0[g].x + y00.y * c0[g].y + y00.z * c0[g].z +
                      y00.w * c0[g].w + y01.x * c1[g].x + y01.y * c1[g].y +
                      y01.z * c1[g].z + y01.w * c1[g].w;
        accO[1][g] += y10.x * c0[g].x + y10.y * c0[g].y + y10.z * c0[g].z +
                      y10.w * c0[g].w + y11.x * c1[g].x + y11.y * c1[g].y +
                      y11.z * c1[g].z + y11.w * c1[g].w;
      }
    }
#pragma unroll
    for (int g = 0; g < 4; ++g) {
      const float bvg = bv[64 * g + lane];
      out[(size_t)(b0 + 0) * kD + 64 * g + lane] = accO[0][g] + bvg;
      out[(size_t)(b0 + 1) * kD + 64 * g + lane] = accO[1][g] + bvg;
    }
  }
}

extern "C" void kernel_launch(void* const* d_in, const int* in_sizes, int n_in,
                              void* d_out, int out_size, void* d_ws,
                              size_t ws_size, hipStream_t stream) {
  const float* x = (const float*)d_in[0];
  const int* mask = (const int*)d_in[1];
  const float* td = (const float*)d_in[2];
  const float* Wq = (const float*)d_in[3];
  const float* bq = (const float*)d_in[4];
  const float* Wk = (const float*)d_in[5];
  const float* bk = (const float*)d_in[6];
  const float* Wv = (const float*)d_in[7];
  const float* bv = (const float*)d_in[8];
  float* ws = (float*)d_ws;  // ~530 KB used
  float* out = (float*)d_out;
  (void)in_sizes; (void)n_in; (void)out_size; (void)ws_size;

  hipLaunchKernelGGL(precomp, dim3(274), dim3(256), 0, stream, Wq, bq, Wk, bk,
                     Wv, ws);
  hipLaunchKernelGGL(fused_main, dim3(kB / 2), dim3(64), 0, stream, x, mask,
                     td, bv, (const float*)ws, out);
}